// Round 10
// baseline (356.326 us; speedup 1.0000x reference)
//
#include <hip/hip_runtime.h>
#include <hip/hip_bf16.h>

#define DIMC 768
#define NSEQ 2048
#define NB 2
#define NH 12
#define HD 64
#define EPSLN 1e-5f
#define LOG2E 1.44269504f

typedef __attribute__((ext_vector_type(8))) short          bf16x8;
typedef __attribute__((ext_vector_type(8))) unsigned short ushort8;
typedef __attribute__((ext_vector_type(4))) unsigned short ushort4v;
typedef __attribute__((ext_vector_type(4))) float          f32x4;
typedef __attribute__((ext_vector_type(2))) unsigned int   u32x2;
typedef unsigned int u32;

__device__ __forceinline__ unsigned short f2b(float f) {
    union { float f; unsigned u; } x; x.f = f;
    unsigned r = x.u + 0x7fffu + ((x.u >> 16) & 1u);   // RNE
    return (unsigned short)(r >> 16);
}
__device__ __forceinline__ float b2f(unsigned short v) {
    union { unsigned u; float f; } x; x.u = ((u32)v) << 16; return x.f;
}

#define MFMA16(a, b, c) __builtin_amdgcn_mfma_f32_16x16x32_bf16((a), (b), (c), 0, 0, 0)

__device__ __forceinline__ void gl_lds16(const unsigned short* g, unsigned short* l) {
    __builtin_amdgcn_global_load_lds(
        (const __attribute__((address_space(1))) u32*)(const void*)g,
        (__attribute__((address_space(3))) u32*)(void*)l, 16, 0, 0);
}

// ---------------------------------------------------------------------------
// Cast pass: f32 -> bf16; merged KVG weight [2304][768] = [wk;wv;gw1],
// g2 = gw[:,768:], wo, and concatenated f32 bias [bk|bv|gb].
// ---------------------------------------------------------------------------
#define G_WQ   147456
#define G_MW   442368
#define G_G2   147456
#define G_WO   147456
#define G_VIS  786432
#define G_INF  786432
#define G_BF_TOTAL (G_WQ + G_MW + G_G2 + G_WO + G_VIS + G_INF)   // 2457600
#define G_BIAS 576
#define G_ALL  (G_BF_TOTAL + G_BIAS)                              // 2458176

__global__ __launch_bounds__(256)
void cast_all_kernel(const float* __restrict__ wq, const float* __restrict__ wk,
                     const float* __restrict__ wv, const float* __restrict__ gw,
                     const float* __restrict__ wo,
                     const float* __restrict__ bk, const float* __restrict__ bv,
                     const float* __restrict__ gb,
                     const float* __restrict__ vis, const float* __restrict__ inf_,
                     unsigned short* __restrict__ o_wq, unsigned short* __restrict__ o_mw,
                     unsigned short* __restrict__ o_g2, unsigned short* __restrict__ o_wo,
                     unsigned short* __restrict__ o_vis, unsigned short* __restrict__ o_inf,
                     float* __restrict__ o_biasc)
{
    const int g = blockIdx.x * 256 + threadIdx.x;
    if (g >= G_ALL) return;
    if (g >= G_BF_TOTAL) {
        const int e0 = (g - G_BF_TOTAL) * 4;
        float4 r;
        float* pr = (float*)&r;
        #pragma unroll
        for (int t = 0; t < 4; ++t) {
            const int e = e0 + t;
            pr[t] = (e < 768) ? bk[e] : (e < 1536) ? bv[e - 768] : gb[e - 1536];
        }
        *(float4*)&o_biasc[e0] = r;
        return;
    }
    const float* src; unsigned short* dst; int soff, doff = 0;
    int gg = g;
    if (gg < G_WQ) { src = wq; dst = o_wq; soff = gg; doff = gg; }
    else if ((gg -= G_WQ) < G_MW) {
        const int row = gg / 192, c4 = gg % 192;
        dst = o_mw; doff = gg;
        if      (row < 768)  { src = wk; soff = row * 192 + c4; }
        else if (row < 1536) { src = wv; soff = (row - 768) * 192 + c4; }
        else                 { src = gw; soff = (row - 1536) * 384 + c4; }
    }
    else if ((gg -= G_MW) < G_G2) {
        const int row = gg / 192, c4 = gg % 192;
        src = gw; soff = row * 384 + 192 + c4; dst = o_g2; doff = gg;
    }
    else if ((gg -= G_G2) < G_WO)  { src = wo;   dst = o_wo;  soff = gg; doff = gg; }
    else if ((gg -= G_WO) < G_VIS) { src = vis;  dst = o_vis; soff = gg; doff = gg; }
    else { gg -= G_VIS;              src = inf_; dst = o_inf; soff = gg; doff = gg; }
    f32x4 v = ((const f32x4*)src)[soff];
    ushort4v t;
    t[0] = f2b(v[0]); t[1] = f2b(v[1]); t[2] = f2b(v[2]); t[3] = f2b(v[3]);
    ((ushort4v*)dst)[doff] = t;
}

// ---------------------------------------------------------------------------
// 128x64 GEMM mainloop (R7/R9-proven): BK=64, 4 waves (2x2), wave tile 64x32,
// LDS dbuf via global_load_lds, counted vmcnt(6). 48 KB LDS -> 3 blocks/CU.
// ---------------------------------------------------------------------------
__device__ __forceinline__ void gemm_core(const unsigned short* __restrict__ A,
                                          const unsigned short* __restrict__ W,
                                          int m0, int n0,
                                          unsigned short* As, unsigned short* Bs,
                                          f32x4 (&acc)[4][2])
{
    const int lane = threadIdx.x & 63, wid = threadIdx.x >> 6;
    const int wm = wid >> 1, wn = wid & 1;
    const int r16 = lane & 15, kg = lane >> 4;
    const int lr = lane >> 3, lc = (lane & 7) * 8;

    auto stage = [&](int k0, int buf) {
        #pragma unroll
        for (int i = 0; i < 4; ++i) {
            const int c = wid * 4 + i;
            gl_lds16(&A[(size_t)(m0 + c * 8 + lr) * DIMC + k0 + lc], &As[buf * 8192 + c * 512]);
        }
        #pragma unroll
        for (int i = 0; i < 2; ++i) {
            const int c = wid * 2 + i;
            gl_lds16(&W[(size_t)(n0 + c * 8 + lr) * DIMC + k0 + lc], &Bs[buf * 4096 + c * 512]);
        }
    };

    stage(0, 0);
    for (int t = 0; t < 12; ++t) {
        const int cur = t & 1;
        if (t < 11) {
            stage((t + 1) * 64, cur ^ 1);
            asm volatile("s_waitcnt vmcnt(6)" ::: "memory");
        } else {
            asm volatile("s_waitcnt vmcnt(0)" ::: "memory");
        }
        __builtin_amdgcn_s_barrier();
        __builtin_amdgcn_sched_barrier(0);
        #pragma unroll
        for (int ks = 0; ks < 2; ++ks) {
            bf16x8 af[4], bg[2];
            #pragma unroll
            for (int mi = 0; mi < 4; ++mi)
                af[mi] = *(const bf16x8*)&As[cur * 8192 + (wm * 64 + mi * 16 + r16) * 64 + ks * 32 + kg * 8];
            #pragma unroll
            for (int nj = 0; nj < 2; ++nj)
                bg[nj] = *(const bf16x8*)&Bs[cur * 4096 + (wn * 32 + nj * 16 + r16) * 64 + ks * 32 + kg * 8];
            __builtin_amdgcn_s_setprio(1);
            #pragma unroll
            for (int mi = 0; mi < 4; ++mi)
                #pragma unroll
                for (int nj = 0; nj < 2; ++nj)
                    acc[mi][nj] = MFMA16(af[mi], bg[nj], acc[mi][nj]);
            __builtin_amdgcn_s_setprio(0);
        }
        __builtin_amdgcn_sched_barrier(0);
        __builtin_amdgcn_s_barrier();
    }
}

// ---------------------------------------------------------------------------
// Phase-1 merged GEMM: [Q-proj | KVG-proj]. 384 + 1152 = 1536 blocks.
// ---------------------------------------------------------------------------
__global__ __launch_bounds__(256)
void gemm_p1(const unsigned short* __restrict__ inf_b, const unsigned short* __restrict__ vis_b,
             const unsigned short* __restrict__ wq_b,  const unsigned short* __restrict__ mw_b,
             const float* __restrict__ bq, const float* __restrict__ biasc,
             unsigned short* __restrict__ qpre,
             unsigned short* __restrict__ k_b, unsigned short* __restrict__ v_b,
             float* __restrict__ Gd)
{
    __shared__ unsigned short As[2 * 8192];
    __shared__ unsigned short Bs[2 * 4096];
    const int bid = (int)blockIdx.x;
    const unsigned short *A, *W;
    int m0, n0, sub;
    if (bid < 384) { sub = 0; const int b = bid;       m0 = (b / 12) * 128; n0 = (b % 12) * 64; A = inf_b; W = wq_b; }
    else           { sub = 1; const int b = bid - 384; m0 = (b / 36) * 128; n0 = (b % 36) * 64; A = vis_b; W = mw_b; }

    f32x4 acc[4][2] = {};
    gemm_core(A, W, m0, n0, As, Bs, acc);

    const int lane = threadIdx.x & 63, wid = threadIdx.x >> 6;
    const int wm = wid >> 1, wn = wid & 1;
    const int r16 = lane & 15, kg = lane >> 4;
    #pragma unroll
    for (int mi = 0; mi < 4; ++mi)
    #pragma unroll
    for (int nj = 0; nj < 2; ++nj) {
        const int gr0 = m0 + wm * 64 + mi * 16 + kg * 4;
        const int gc  = n0 + wn * 32 + nj * 16 + r16;
        #pragma unroll
        for (int r = 0; r < 4; ++r) {
            const int gr = gr0 + r;
            float val = acc[mi][nj][r];
            if (sub == 0) {
                qpre[(size_t)gr * DIMC + gc] = f2b(val + bq[gc]);
            } else {
                val += biasc[gc];
                if      (gc < 768)  k_b[(size_t)gr * DIMC + gc] = f2b(val);
                else if (gc < 1536) v_b[(size_t)gr * DIMC + (gc - 768)] = f2b(val);
                else                Gd[(size_t)gr * DIMC + (gc - 1536)] = val;
            }
        }
    }
}

// ---------------------------------------------------------------------------
// wo projection: Oc f32 = attnO @ wo^T + bo, plus bf16 copy oc_b. 384 blocks.
// ---------------------------------------------------------------------------
__global__ __launch_bounds__(256)
void gemm_wo(const unsigned short* __restrict__ ao_b, const unsigned short* __restrict__ wo_b,
             const float* __restrict__ bo,
             float* __restrict__ Oc, unsigned short* __restrict__ oc_b)
{
    __shared__ unsigned short As[2 * 8192];
    __shared__ unsigned short Bs[2 * 4096];
    const int bid = (int)blockIdx.x;
    const int m0 = (bid / 12) * 128, n0 = (bid % 12) * 64;

    f32x4 acc[4][2] = {};
    gemm_core(ao_b, wo_b, m0, n0, As, Bs, acc);

    const int lane = threadIdx.x & 63, wid = threadIdx.x >> 6;
    const int wm = wid >> 1, wn = wid & 1;
    const int r16 = lane & 15, kg = lane >> 4;
    #pragma unroll
    for (int mi = 0; mi < 4; ++mi)
    #pragma unroll
    for (int nj = 0; nj < 2; ++nj) {
        const int gr0 = m0 + wm * 64 + mi * 16 + kg * 4;
        const int gc  = n0 + wn * 32 + nj * 16 + r16;
        #pragma unroll
        for (int r = 0; r < 4; ++r) {
            const size_t idx = (size_t)(gr0 + r) * DIMC + gc;
            const float val = acc[mi][nj][r] + bo[gc];
            Oc[idx] = val;
            oc_b[idx] = f2b(val);
        }
    }
}

// ---------------------------------------------------------------------------
// gate2: Gd += oc_b @ g2^T. 384 blocks.
// ---------------------------------------------------------------------------
__global__ __launch_bounds__(256)
void gemm_g2(const unsigned short* __restrict__ oc_b, const unsigned short* __restrict__ g2_b,
             float* __restrict__ Gd)
{
    __shared__ unsigned short As[2 * 8192];
    __shared__ unsigned short Bs[2 * 4096];
    const int bid = (int)blockIdx.x;
    const int m0 = (bid / 12) * 128, n0 = (bid % 12) * 64;

    f32x4 acc[4][2] = {};
    gemm_core(oc_b, g2_b, m0, n0, As, Bs, acc);

    const int lane = threadIdx.x & 63, wid = threadIdx.x >> 6;
    const int wm = wid >> 1, wn = wid & 1;
    const int r16 = lane & 15, kg = lane >> 4;
    #pragma unroll
    for (int mi = 0; mi < 4; ++mi)
    #pragma unroll
    for (int nj = 0; nj < 2; ++nj) {
        const int gr0 = m0 + wm * 64 + mi * 16 + kg * 4;
        const int gc  = n0 + wn * 32 + nj * 16 + r16;
        #pragma unroll
        for (int r = 0; r < 4; ++r)
            Gd[(size_t)(gr0 + r) * DIMC + gc] += acc[mi][nj][r];
    }
}

// ---------------------------------------------------------------------------
// Merged LayerNorm: grid 12288. mode 0: qpre bf16 -> q_b. mode 1: K in-place
// (+0.125*log2e scale + pos*log2e). mode 2: V in-place.
// ---------------------------------------------------------------------------
__global__ __launch_bounds__(256)
void ln_all_kernel(const unsigned short* __restrict__ qpre,
                   const float* __restrict__ lnqw, const float* __restrict__ lnqb,
                   const float* __restrict__ lnkw, const float* __restrict__ lnkb,
                   const float* __restrict__ lnvw, const float* __restrict__ lnvb,
                   const float* __restrict__ pos,
                   unsigned short* __restrict__ q_b,
                   unsigned short* __restrict__ k_b, unsigned short* __restrict__ v_b)
{
    const int bid = blockIdx.x;
    const int mode = bid >> 12;           // 0,1,2
    const int row = bid & 4095;
    const int n = row & (NSEQ - 1);
    const unsigned short* src;
    unsigned short* dst;
    const float *w, *b;
    if (mode == 0)      { src = qpre + (size_t)row * DIMC; dst = q_b + (size_t)row * DIMC; w = lnqw; b = lnqb; }
    else if (mode == 1) { src = dst = k_b + (size_t)row * DIMC; w = lnkw; b = lnkb; }
    else                { src = dst = v_b + (size_t)row * DIMC; w = lnvw; b = lnvb; }

    float x[3];
    float s = 0.f, q = 0.f;
    #pragma unroll
    for (int u = 0; u < 3; ++u) {
        const int j = threadIdx.x + u * 256;
        x[u] = b2f(src[j]);
        s += x[u];
        q += x[u] * x[u];
    }
    #pragma unroll
    for (int off = 32; off > 0; off >>= 1) {
        s += __shfl_down(s, off);
        q += __shfl_down(q, off);
    }
    __shared__ float ls[8];
    const int wv_ = threadIdx.x >> 6;
    if ((threadIdx.x & 63) == 0) { ls[wv_] = s; ls[4 + wv_] = q; }
    __syncthreads();
    if (threadIdx.x == 0) {
        ls[0] = ls[0] + ls[1] + ls[2] + ls[3];
        ls[4] = ls[4] + ls[5] + ls[6] + ls[7];
    }
    __syncthreads();
    const float mu  = ls[0] * (1.f / DIMC);
    const float var = ls[4] * (1.f / DIMC) - mu * mu;
    const float rs  = rsqrtf(var + EPSLN);
    #pragma unroll
    for (int u = 0; u < 3; ++u) {
        const int j = threadIdx.x + u * 256;
        float y = (x[u] - mu) * rs * w[j] + b[j];
        if (mode == 1) y = y * (0.125f * LOG2E) + pos[(size_t)n * DIMC + j] * LOG2E;
        dst[j] = f2b(y);
    }
}

// ---------------------------------------------------------------------------
// Swapped-QK^T flash attention v4: K fragments loaded DIRECTLY from global
// (L2-resident; contiguous 16B per lane) -- Ks LDS eliminated (-42% LDS
// traffic, -Ks bank conflicts). V stays LDS-transposed; Ps per-wave LDS.
// 64 q-rows/block, KVBLK=128, V register prefetch, defer-max. Grid (24,32).
// ---------------------------------------------------------------------------
__global__ __launch_bounds__(256, 3)
void attn_bf16_kernel(const unsigned short* __restrict__ Q,
                      const unsigned short* __restrict__ K,
                      const unsigned short* __restrict__ V,
                      unsigned short* __restrict__ O)
{
    __shared__ unsigned short Vt[64][136];
    __shared__ unsigned short Ps[4][16][136];

    const int bh = blockIdx.x;
    const int b = bh / NH, h = bh % NH;
    const int n0 = blockIdx.y * 64;
    const int tid = threadIdx.x;
    const int lane = tid & 63, w = tid >> 6;
    const int r16 = lane & 15, kg = lane >> 4;

    const size_t base = (size_t)b * NSEQ * DIMC + (size_t)h * HD;

    // Q fragments (B-operand): col q = r16 (wave-local), k = d
    const size_t qoff = base + (size_t)(n0 + w * 16 + r16) * DIMC + kg * 8;
    bf16x8 aq0 = *(const bf16x8*)&Q[qoff];
    bf16x8 aq1 = *(const bf16x8*)&Q[qoff + 32];

    // per-lane K fragment base: row r16 (+16f +m0), k-col kg*8 (+32 for hi)
    const unsigned short* Kf = K + base + (size_t)r16 * DIMC + kg * 8;

    // V staging coords
    const int vkv = lane;
    const int vdc = w * 16;
    const unsigned short* Vg = V + base + (size_t)vkv * DIMC + vdc;

    f32x4 o[4] = {};
    float m_run = -1e30f, l_run = 0.f;

    ushort8 pv[2][2];
    auto pf_load = [&](size_t adv) {
        #pragma unroll
        for (int rep = 0; rep < 2; ++rep)
            #pragma unroll
            for (int hh = 0; hh < 2; ++hh)
                pv[rep][hh] = *(const ushort8*)(Vg + adv + (size_t)rep * 64 * DIMC + hh * 8);
    };
    auto pf_write = [&]() {
        #pragma unroll
        for (int rep = 0; rep < 2; ++rep)
            #pragma unroll
            for (int hh = 0; hh < 2; ++hh)
                #pragma unroll
                for (int e = 0; e < 8; ++e)
                    Vt[vdc + hh * 8 + e][vkv + rep * 64] = pv[rep][hh][e];
    };

    pf_load(0);
    pf_write();
    __syncthreads();

    for (int m0 = 0; m0 < NSEQ; m0 += 128) {
        const bool more = (m0 + 128 < NSEQ);

        // K fragments for THIS tile, direct from global (16 x 16B per lane)
        bf16x8 kb[8][2];
        {
            const unsigned short* Kt = Kf + (size_t)m0 * DIMC;
            #pragma unroll
            for (int f = 0; f < 8; ++f) {
                kb[f][0] = *(const bf16x8*)(Kt + (size_t)(f * 16) * DIMC);
                kb[f][1] = *(const bf16x8*)(Kt + (size_t)(f * 16) * DIMC + 32);
            }
        }
        if (more) pf_load((size_t)(m0 + 128) * DIMC);   // next V tile -> regs
        __builtin_amdgcn_sched_barrier(0);

        // S^T = mfma(K, Q): lane holds P[q=r16][kv = f*16 + kg*4 + j]
        f32x4 sv[8];
        #pragma unroll
        for (int f = 0; f < 8; ++f) sv[f] = (f32x4){0.f, 0.f, 0.f, 0.f};
        __builtin_amdgcn_s_setprio(1);
        #pragma unroll
        for (int f = 0; f < 8; ++f) {
            sv[f] = MFMA16(kb[f][0], aq0, sv[f]);
            sv[f] = MFMA16(kb[f][1], aq1, sv[f]);
        }
        __builtin_amdgcn_s_setprio(0);

        // tree max over 32 values
        float mf[8];
        #pragma unroll
        for (int f = 0; f < 8; ++f)
            mf[f] = fmaxf(fmaxf(sv[f][0], sv[f][1]), fmaxf(sv[f][2], sv[f][3]));
        float m01 = fmaxf(mf[0], mf[1]), m23 = fmaxf(mf[2], mf[3]);
        float m45 = fmaxf(mf[4], mf[5]), m67 = fmaxf(mf[6], mf[7]);
        float mt = fmaxf(fmaxf(m01, m23), fmaxf(m45, m67));
        mt = fmaxf(mt, __shfl_xor(mt, 16));
        mt = fmaxf(mt, __shfl_xor(mt, 32));

        const bool defer = __all(mt - m_run <= 8.0f);
        float corr = 1.f;
        if (!defer) {
            const float mn = fmaxf(m_run, mt);
            corr = exp2f(m_run - mn);
            m_run = mn;
        }

        // exp, tree sum, pack P -> per-wave slab
        float sf[8];
        #pragma unroll
        for (int f = 0; f < 8; ++f) {
            float p0 = exp2f(sv[f][0] - m_run);
            float p1 = exp2f(sv[f][1] - m_run);
            float p2 = exp2f(sv[f][2] - m_run);
            float p3 = exp2f(sv[f][3] - m_run);
            sf[f] = (p0 + p1) + (p2 + p3);
            u32 w0, w1;
            asm("v_cvt_pk_bf16_f32 %0, %1, %2" : "=v"(w0) : "v"(p0), "v"(p1));
            asm("v_cvt_pk_bf16_f32 %0, %1, %2" : "=v"(w1) : "v"(p2), "v"(p3));
            u32x2 pw; pw[0] = w0; pw[1] = w1;
            *(u32x2*)&Ps[w][r16][f * 16 + kg * 4] = pw;
        }
        float st = ((sf[0] + sf[1]) + (sf[2] + sf[3])) + ((sf[4] + sf[5]) + (sf[6] + sf[7]));
        st += __shfl_xor(st, 16);
        st += __shfl_xor(st, 32);
        l_run = l_run * corr + st;

        if (!defer) {
            #pragma unroll
            for (int jj = 0; jj < 4; ++jj) {
                const float cq = __shfl(corr, kg * 4 + jj);
                o[0][jj] *= cq; o[1][jj] *= cq; o[2][jj] *= cq; o[3][jj] *= cq;
            }
        }

        // O += P @ V (k = 128: 4 A-frags x 4 d-frags)
        bf16x8 pa[4];
        #pragma unroll
        for (int s = 0; s < 4; ++s)
            pa[s] = *(const bf16x8*)&Ps[w][r16][s * 32 + kg * 8];
        __builtin_amdgcn_s_setprio(1);
        #pragma unroll
        for (int nj = 0; nj < 4; ++nj) {
            #pragma unroll
            for (int s = 0; s < 4; ++s) {
                bf16x8 vb = *(const bf16x8*)&Vt[nj * 16 + r16][s * 32 + kg * 8];
                o[nj] = MFMA16(pa[s], vb, o[nj]);
            }
        }
        __builtin_amdgcn_s_setprio(0);

        // all waves done reading Vt -> overwrite with prefetched tile
        __builtin_amdgcn_s_barrier();
        __builtin_amdgcn_sched_barrier(0);
        if (more) pf_write();
        __syncthreads();
    }

    const float linv = 1.f / l_run;
    #pragma unroll
    for (int jj = 0; jj < 4; ++jj) {
        const float cq = __shfl(linv, kg * 4 + jj);
        #pragma unroll
        for (int nj = 0; nj < 4; ++nj) {
            const size_t go = base + (size_t)(n0 + w * 16 + kg * 4 + jj) * DIMC + nj * 16 + r16;
            O[go] = f2b(o[nj][jj] * cq);
        }
    }
}

// ---------------------------------------------------------------------------
// gate = sigmoid(G); fused = vis*g + Oc*(1-g); out = LN(fused).
// ---------------------------------------------------------------------------
__global__ __launch_bounds__(256)
void fuse_ln_kernel(const float* __restrict__ vis,
                    const float* __restrict__ Oc,
                    const float* __restrict__ G,
                    const float* __restrict__ w,
                    const float* __restrict__ b,
                    float* __restrict__ out)
{
    const int row = blockIdx.x;
    float f[3];
    float s = 0.f, q = 0.f;
    #pragma unroll
    for (int u = 0; u < 3; ++u) {
        const size_t idx = (size_t)row * DIMC + threadIdx.x + u * 256;
        const float vv = vis[idx];
        const float oo = Oc[idx];
        const float gg = 1.f / (1.f + __expf(-G[idx]));
        f[u] = vv * gg + oo * (1.f - gg);
        s += f[u];
        q += f[u] * f[u];
    }
    #pragma unroll
    for (int off = 32; off > 0; off >>= 1) {
        s += __shfl_down(s, off);
        q += __shfl_down(q, off);
    }
    __shared__ float ls[8];
    const int wv_ = threadIdx.x >> 6;
    if ((threadIdx.x & 63) == 0) { ls[wv_] = s; ls[4 + wv_] = q; }
    __syncthreads();
    if (threadIdx.x == 0) {
        ls[0] = ls[0] + ls[1] + ls[2] + ls[3];
        ls[4] = ls[4] + ls[5] + ls[6] + ls[7];
    }
    __syncthreads();
    const float mu  = ls[0] * (1.f / DIMC);
    const float var = ls[4] * (1.f / DIMC) - mu * mu;
    const float rs  = rsqrtf(var + EPSLN);
    #pragma unroll
    for (int u = 0; u < 3; ++u) {
        const int j = threadIdx.x + u * 256;
        out[(size_t)row * DIMC + j] = (f[u] - mu) * rs * w[j] + b[j];
    }
}

// ---------------------------------------------------------------------------
extern "C" void kernel_launch(void* const* d_in, const int* in_sizes, int n_in,
                              void* d_out, int out_size, void* d_ws, size_t ws_size,
                              hipStream_t stream)
{
    const float* vis  = (const float*)d_in[0];
    const float* inf_ = (const float*)d_in[1];
    const float* wq   = (const float*)d_in[2];
    const float* bq   = (const float*)d_in[3];
    const float* lnqw = (const float*)d_in[4];
    const float* lnqb = (const float*)d_in[5];
    const float* wk   = (const float*)d_in[6];
    const float* bk   = (const float*)d_in[7];
    const float* lnkw = (const float*)d_in[8];
    const float* lnkb = (const float*)d_in[9];
    const float* wv   = (const float*)d_in[10];
    const float* bv   = (const float*)d_in[11];
    const float* lnvw = (const float*)d_in[12];
    const float* lnvb = (const float*)d_in[13];
    const float* pos  = (const float*)d_in[14];
    const float* wo   = (const float*)d_in[15];
    const float* bo   = (const float*)d_in[16];
    const float* gw   = (const float*)d_in[17];
    const float* gb   = (const float*)d_in[18];
    const float* lnw  = (const float*)d_in[19];
    const float* lnb  = (const float*)d_in[20];

    const size_t WEL = 589824;                    // 768*768
    const size_t MWEL = 1769472;                  // 2304*768
    const size_t BUF = (size_t)NB * NSEQ * DIMC;  // 3145728

    // WS total = 43.9 MiB (safe < 51 proven; R6's 53.5 overflowed)
    unsigned short* p = (unsigned short*)d_ws;
    unsigned short* wq_b   = p;  p += WEL;
    unsigned short* mw_b   = p;  p += MWEL;   // [wk;wv;gw1]
    unsigned short* g2_b   = p;  p += WEL;    // gw2 bf16
    unsigned short* wo_b   = p;  p += WEL;    // wo bf16
    unsigned short* vis_b  = p;  p += BUF;
    unsigned short* inf_b  = p;  p += BUF;
    unsigned short* qpre_b = p;  p += BUF;    // pre-LN Q bf16; oc_b post-attn
    unsigned short* q_b    = p;  p += BUF;    // post-LN Q; attn O in place
    unsigned short* k_b    = p;  p += BUF;    // pre-LN K -> in-place LN'd K
    unsigned short* v_b    = p;  p += BUF;    // pre-LN V -> in-place LN'd V
    float* biasc = (float*)p;   p += 4608;    // [bk|bv|gb] f32 (2304)

    float* Gd = (float*)d_out;             // gate logits accumulator
    float* Oc = (float*)k_b;               // f32 O-proj (k_b+v_b, dead post-attn)
    unsigned short* oc_b = qpre_b;         // bf16 O-proj (qpre dead post-LN)

    dim3 blk(256);

    cast_all_kernel<<<dim3((G_ALL + 255) / 256), blk, 0, stream>>>(
        wq, wk, wv, gw, wo, bk, bv, gb, vis, inf_,
        wq_b, mw_b, g2_b, wo_b, vis_b, inf_b, biasc);

    // merged: Q-proj -> qpre_b | KVG -> k_b,v_b,Gd
    gemm_p1<<<dim3(1536), blk, 0, stream>>>(inf_b, vis_b, wq_b, mw_b,
                                            bq, biasc, qpre_b, k_b, v_b, Gd);

    // all three LayerNorms in one launch
    ln_all_kernel<<<dim3(12288), blk, 0, stream>>>(qpre_b, lnqw, lnqb, lnkw, lnkb,
                                                   lnvw, lnvb, pos, q_b, k_b, v_b);

    // attention (O overwrites q_b in place)
    attn_bf16_kernel<<<dim3(NB * NH, NSEQ / 64), blk, 0, stream>>>(q_b, k_b, v_b, q_b);

    // Oc = attnO@wo^T + bo (f32 + bf16)
    gemm_wo<<<dim3(384), blk, 0, stream>>>(q_b, wo_b, bo, Oc, oc_b);

    // Gd += Oc@gw2^T
    gemm_g2<<<dim3(384), blk, 0, stream>>>(oc_b, g2_b, Gd);

    // fuse + final LN -> d_out
    fuse_ln_kernel<<<dim3(4096), blk, 0, stream>>>(vis, Oc, Gd, lnw, lnb, (float*)d_out);
}

// Round 11
// 295.901 us; speedup vs baseline: 1.2042x; 1.2042x over previous
//
#include <hip/hip_runtime.h>
#include <hip/hip_bf16.h>

#define DIMC 768
#define NSEQ 2048
#define NB 2
#define NH 12
#define HD 64
#define EPSLN 1e-5f
#define LOG2E 1.44269504f

typedef __attribute__((ext_vector_type(8))) short          bf16x8;
typedef __attribute__((ext_vector_type(8))) unsigned short ushort8;
typedef __attribute__((ext_vector_type(4))) unsigned short ushort4v;
typedef __attribute__((ext_vector_type(4))) float          f32x4;
typedef __attribute__((ext_vector_type(2))) unsigned int   u32x2;
typedef unsigned int u32;

__device__ __forceinline__ unsigned short f2b(float f) {
    union { float f; unsigned u; } x; x.f = f;
    unsigned r = x.u + 0x7fffu + ((x.u >> 16) & 1u);   // RNE
    return (unsigned short)(r >> 16);
}
__device__ __forceinline__ float b2f(unsigned short v) {
    union { unsigned u; float f; } x; x.u = ((u32)v) << 16; return x.f;
}

#define MFMA16(a, b, c) __builtin_amdgcn_mfma_f32_16x16x32_bf16((a), (b), (c), 0, 0, 0)

__device__ __forceinline__ void gl_lds16(const unsigned short* g, unsigned short* l) {
    __builtin_amdgcn_global_load_lds(
        (const __attribute__((address_space(1))) u32*)(const void*)g,
        (__attribute__((address_space(3))) u32*)(void*)l, 16, 0, 0);
}

// ---------------------------------------------------------------------------
// Cast pass: f32 -> bf16; merged KVG weight [2304][768] = [wk;wv;gw1],
// g2 = gw[:,768:], wo, and concatenated f32 bias [bk|bv|gb].
// ---------------------------------------------------------------------------
#define G_WQ   147456
#define G_MW   442368
#define G_G2   147456
#define G_WO   147456
#define G_VIS  786432
#define G_INF  786432
#define G_BF_TOTAL (G_WQ + G_MW + G_G2 + G_WO + G_VIS + G_INF)   // 2457600
#define G_BIAS 576
#define G_ALL  (G_BF_TOTAL + G_BIAS)                              // 2458176

__global__ __launch_bounds__(256)
void cast_all_kernel(const float* __restrict__ wq, const float* __restrict__ wk,
                     const float* __restrict__ wv, const float* __restrict__ gw,
                     const float* __restrict__ wo,
                     const float* __restrict__ bk, const float* __restrict__ bv,
                     const float* __restrict__ gb,
                     const float* __restrict__ vis, const float* __restrict__ inf_,
                     unsigned short* __restrict__ o_wq, unsigned short* __restrict__ o_mw,
                     unsigned short* __restrict__ o_g2, unsigned short* __restrict__ o_wo,
                     unsigned short* __restrict__ o_vis, unsigned short* __restrict__ o_inf,
                     float* __restrict__ o_biasc)
{
    const int g = blockIdx.x * 256 + threadIdx.x;
    if (g >= G_ALL) return;
    if (g >= G_BF_TOTAL) {
        const int e0 = (g - G_BF_TOTAL) * 4;
        float4 r;
        float* pr = (float*)&r;
        #pragma unroll
        for (int t = 0; t < 4; ++t) {
            const int e = e0 + t;
            pr[t] = (e < 768) ? bk[e] : (e < 1536) ? bv[e - 768] : gb[e - 1536];
        }
        *(float4*)&o_biasc[e0] = r;
        return;
    }
    const float* src; unsigned short* dst; int soff, doff = 0;
    int gg = g;
    if (gg < G_WQ) { src = wq; dst = o_wq; soff = gg; doff = gg; }
    else if ((gg -= G_WQ) < G_MW) {
        const int row = gg / 192, c4 = gg % 192;
        dst = o_mw; doff = gg;
        if      (row < 768)  { src = wk; soff = row * 192 + c4; }
        else if (row < 1536) { src = wv; soff = (row - 768) * 192 + c4; }
        else                 { src = gw; soff = (row - 1536) * 384 + c4; }
    }
    else if ((gg -= G_MW) < G_G2) {
        const int row = gg / 192, c4 = gg % 192;
        src = gw; soff = row * 384 + 192 + c4; dst = o_g2; doff = gg;
    }
    else if ((gg -= G_G2) < G_WO)  { src = wo;   dst = o_wo;  soff = gg; doff = gg; }
    else if ((gg -= G_WO) < G_VIS) { src = vis;  dst = o_vis; soff = gg; doff = gg; }
    else { gg -= G_VIS;              src = inf_; dst = o_inf; soff = gg; doff = gg; }
    f32x4 v = ((const f32x4*)src)[soff];
    ushort4v t;
    t[0] = f2b(v[0]); t[1] = f2b(v[1]); t[2] = f2b(v[2]); t[3] = f2b(v[3]);
    ((ushort4v*)dst)[doff] = t;
}

// ---------------------------------------------------------------------------
// 128x64 GEMM mainloop (R7/R9-proven): BK=64, 4 waves (2x2), wave tile 64x32,
// LDS dbuf via global_load_lds, counted vmcnt(6). 48 KB LDS -> 3 blocks/CU.
// ---------------------------------------------------------------------------
__device__ __forceinline__ void gemm_core(const unsigned short* __restrict__ A,
                                          const unsigned short* __restrict__ W,
                                          int m0, int n0,
                                          unsigned short* As, unsigned short* Bs,
                                          f32x4 (&acc)[4][2])
{
    const int lane = threadIdx.x & 63, wid = threadIdx.x >> 6;
    const int wm = wid >> 1, wn = wid & 1;
    const int r16 = lane & 15, kg = lane >> 4;
    const int lr = lane >> 3, lc = (lane & 7) * 8;

    auto stage = [&](int k0, int buf) {
        #pragma unroll
        for (int i = 0; i < 4; ++i) {
            const int c = wid * 4 + i;
            gl_lds16(&A[(size_t)(m0 + c * 8 + lr) * DIMC + k0 + lc], &As[buf * 8192 + c * 512]);
        }
        #pragma unroll
        for (int i = 0; i < 2; ++i) {
            const int c = wid * 2 + i;
            gl_lds16(&W[(size_t)(n0 + c * 8 + lr) * DIMC + k0 + lc], &Bs[buf * 4096 + c * 512]);
        }
    };

    stage(0, 0);
    for (int t = 0; t < 12; ++t) {
        const int cur = t & 1;
        if (t < 11) {
            stage((t + 1) * 64, cur ^ 1);
            asm volatile("s_waitcnt vmcnt(6)" ::: "memory");
        } else {
            asm volatile("s_waitcnt vmcnt(0)" ::: "memory");
        }
        __builtin_amdgcn_s_barrier();
        __builtin_amdgcn_sched_barrier(0);
        #pragma unroll
        for (int ks = 0; ks < 2; ++ks) {
            bf16x8 af[4], bg[2];
            #pragma unroll
            for (int mi = 0; mi < 4; ++mi)
                af[mi] = *(const bf16x8*)&As[cur * 8192 + (wm * 64 + mi * 16 + r16) * 64 + ks * 32 + kg * 8];
            #pragma unroll
            for (int nj = 0; nj < 2; ++nj)
                bg[nj] = *(const bf16x8*)&Bs[cur * 4096 + (wn * 32 + nj * 16 + r16) * 64 + ks * 32 + kg * 8];
            __builtin_amdgcn_s_setprio(1);
            #pragma unroll
            for (int mi = 0; mi < 4; ++mi)
                #pragma unroll
                for (int nj = 0; nj < 2; ++nj)
                    acc[mi][nj] = MFMA16(af[mi], bg[nj], acc[mi][nj]);
            __builtin_amdgcn_s_setprio(0);
        }
        __builtin_amdgcn_sched_barrier(0);
        __builtin_amdgcn_s_barrier();
    }
}

// ---------------------------------------------------------------------------
// Phase-1 merged GEMM: [Q-proj | KVG-proj]. 384 + 1152 = 1536 blocks.
// XCD-chunked swizzle (1536 % 8 == 0): each XCD gets contiguous m-panels.
// ---------------------------------------------------------------------------
__global__ __launch_bounds__(256)
void gemm_p1(const unsigned short* __restrict__ inf_b, const unsigned short* __restrict__ vis_b,
             const unsigned short* __restrict__ wq_b,  const unsigned short* __restrict__ mw_b,
             const float* __restrict__ bq, const float* __restrict__ biasc,
             unsigned short* __restrict__ qpre,
             unsigned short* __restrict__ k_b, unsigned short* __restrict__ v_b,
             float* __restrict__ Gd)
{
    __shared__ unsigned short As[2 * 8192];
    __shared__ unsigned short Bs[2 * 4096];
    int bid = (int)blockIdx.x;
    bid = (bid & 7) * 192 + (bid >> 3);        // XCD swizzle
    const unsigned short *A, *W;
    int m0, n0, sub;
    if (bid < 384) { sub = 0; const int b = bid;       m0 = (b / 12) * 128; n0 = (b % 12) * 64; A = inf_b; W = wq_b; }
    else           { sub = 1; const int b = bid - 384; m0 = (b / 36) * 128; n0 = (b % 36) * 64; A = vis_b; W = mw_b; }

    f32x4 acc[4][2] = {};
    gemm_core(A, W, m0, n0, As, Bs, acc);

    const int lane = threadIdx.x & 63, wid = threadIdx.x >> 6;
    const int wm = wid >> 1, wn = wid & 1;
    const int r16 = lane & 15, kg = lane >> 4;
    #pragma unroll
    for (int mi = 0; mi < 4; ++mi)
    #pragma unroll
    for (int nj = 0; nj < 2; ++nj) {
        const int gr0 = m0 + wm * 64 + mi * 16 + kg * 4;
        const int gc  = n0 + wn * 32 + nj * 16 + r16;
        #pragma unroll
        for (int r = 0; r < 4; ++r) {
            const int gr = gr0 + r;
            float val = acc[mi][nj][r];
            if (sub == 0) {
                qpre[(size_t)gr * DIMC + gc] = f2b(val + bq[gc]);
            } else {
                val += biasc[gc];
                if      (gc < 768)  k_b[(size_t)gr * DIMC + gc] = f2b(val);
                else if (gc < 1536) v_b[(size_t)gr * DIMC + (gc - 768)] = f2b(val);
                else                Gd[(size_t)gr * DIMC + (gc - 1536)] = val;
            }
        }
    }
}

// ---------------------------------------------------------------------------
// wo projection: Oc f32 = attnO @ wo^T + bo, plus bf16 copy oc_b. 384 blocks.
// ---------------------------------------------------------------------------
__global__ __launch_bounds__(256)
void gemm_wo(const unsigned short* __restrict__ ao_b, const unsigned short* __restrict__ wo_b,
             const float* __restrict__ bo,
             float* __restrict__ Oc, unsigned short* __restrict__ oc_b)
{
    __shared__ unsigned short As[2 * 8192];
    __shared__ unsigned short Bs[2 * 4096];
    int bid = (int)blockIdx.x;
    bid = (bid & 7) * 48 + (bid >> 3);         // XCD swizzle (384 % 8 == 0)
    const int m0 = (bid / 12) * 128, n0 = (bid % 12) * 64;

    f32x4 acc[4][2] = {};
    gemm_core(ao_b, wo_b, m0, n0, As, Bs, acc);

    const int lane = threadIdx.x & 63, wid = threadIdx.x >> 6;
    const int wm = wid >> 1, wn = wid & 1;
    const int r16 = lane & 15, kg = lane >> 4;
    #pragma unroll
    for (int mi = 0; mi < 4; ++mi)
    #pragma unroll
    for (int nj = 0; nj < 2; ++nj) {
        const int gr0 = m0 + wm * 64 + mi * 16 + kg * 4;
        const int gc  = n0 + wn * 32 + nj * 16 + r16;
        #pragma unroll
        for (int r = 0; r < 4; ++r) {
            const size_t idx = (size_t)(gr0 + r) * DIMC + gc;
            const float val = acc[mi][nj][r] + bo[gc];
            Oc[idx] = val;
            oc_b[idx] = f2b(val);
        }
    }
}

// ---------------------------------------------------------------------------
// gate2: Gd += oc_b @ g2^T. 384 blocks.
// ---------------------------------------------------------------------------
__global__ __launch_bounds__(256)
void gemm_g2(const unsigned short* __restrict__ oc_b, const unsigned short* __restrict__ g2_b,
             float* __restrict__ Gd)
{
    __shared__ unsigned short As[2 * 8192];
    __shared__ unsigned short Bs[2 * 4096];
    int bid = (int)blockIdx.x;
    bid = (bid & 7) * 48 + (bid >> 3);         // XCD swizzle (384 % 8 == 0)
    const int m0 = (bid / 12) * 128, n0 = (bid % 12) * 64;

    f32x4 acc[4][2] = {};
    gemm_core(oc_b, g2_b, m0, n0, As, Bs, acc);

    const int lane = threadIdx.x & 63, wid = threadIdx.x >> 6;
    const int wm = wid >> 1, wn = wid & 1;
    const int r16 = lane & 15, kg = lane >> 4;
    #pragma unroll
    for (int mi = 0; mi < 4; ++mi)
    #pragma unroll
    for (int nj = 0; nj < 2; ++nj) {
        const int gr0 = m0 + wm * 64 + mi * 16 + kg * 4;
        const int gc  = n0 + wn * 32 + nj * 16 + r16;
        #pragma unroll
        for (int r = 0; r < 4; ++r)
            Gd[(size_t)(gr0 + r) * DIMC + gc] += acc[mi][nj][r];
    }
}

// ---------------------------------------------------------------------------
// Merged LayerNorm: grid 12288. mode 0: qpre bf16 -> q_b. mode 1: K in-place
// (+0.125*log2e scale + pos*log2e). mode 2: V in-place.
// ---------------------------------------------------------------------------
__global__ __launch_bounds__(256)
void ln_all_kernel(const unsigned short* __restrict__ qpre,
                   const float* __restrict__ lnqw, const float* __restrict__ lnqb,
                   const float* __restrict__ lnkw, const float* __restrict__ lnkb,
                   const float* __restrict__ lnvw, const float* __restrict__ lnvb,
                   const float* __restrict__ pos,
                   unsigned short* __restrict__ q_b,
                   unsigned short* __restrict__ k_b, unsigned short* __restrict__ v_b)
{
    const int bid = blockIdx.x;
    const int mode = bid >> 12;           // 0,1,2
    const int row = bid & 4095;
    const int n = row & (NSEQ - 1);
    const unsigned short* src;
    unsigned short* dst;
    const float *w, *b;
    if (mode == 0)      { src = qpre + (size_t)row * DIMC; dst = q_b + (size_t)row * DIMC; w = lnqw; b = lnqb; }
    else if (mode == 1) { src = dst = k_b + (size_t)row * DIMC; w = lnkw; b = lnkb; }
    else                { src = dst = v_b + (size_t)row * DIMC; w = lnvw; b = lnvb; }

    float x[3];
    float s = 0.f, q = 0.f;
    #pragma unroll
    for (int u = 0; u < 3; ++u) {
        const int j = threadIdx.x + u * 256;
        x[u] = b2f(src[j]);
        s += x[u];
        q += x[u] * x[u];
    }
    #pragma unroll
    for (int off = 32; off > 0; off >>= 1) {
        s += __shfl_down(s, off);
        q += __shfl_down(q, off);
    }
    __shared__ float ls[8];
    const int wv_ = threadIdx.x >> 6;
    if ((threadIdx.x & 63) == 0) { ls[wv_] = s; ls[4 + wv_] = q; }
    __syncthreads();
    if (threadIdx.x == 0) {
        ls[0] = ls[0] + ls[1] + ls[2] + ls[3];
        ls[4] = ls[4] + ls[5] + ls[6] + ls[7];
    }
    __syncthreads();
    const float mu  = ls[0] * (1.f / DIMC);
    const float var = ls[4] * (1.f / DIMC) - mu * mu;
    const float rs  = rsqrtf(var + EPSLN);
    #pragma unroll
    for (int u = 0; u < 3; ++u) {
        const int j = threadIdx.x + u * 256;
        float y = (x[u] - mu) * rs * w[j] + b[j];
        if (mode == 1) y = y * (0.125f * LOG2E) + pos[(size_t)n * DIMC + j] * LOG2E;
        dst[j] = f2b(y);
    }
}

// ---------------------------------------------------------------------------
// Swapped-QK^T flash attention v3 (R9 verbatim, 78.2 µs proven — R10's
// K-from-global variant was latency-bound, 136 µs; Ks LDS staging restored).
// 64 q-rows/block, KVBLK=128, register prefetch, defer-max, tree reductions.
// ---------------------------------------------------------------------------
__global__ __launch_bounds__(256, 3)
void attn_bf16_kernel(const unsigned short* __restrict__ Q,
                      const unsigned short* __restrict__ K,
                      const unsigned short* __restrict__ V,
                      unsigned short* __restrict__ O)
{
    __shared__ unsigned short Ks[128][72];
    __shared__ unsigned short Vt[64][136];
    __shared__ unsigned short Ps[4][16][136];

    const int bh = blockIdx.x;
    const int b = bh / NH, h = bh % NH;
    const int n0 = blockIdx.y * 64;
    const int tid = threadIdx.x;
    const int lane = tid & 63, w = tid >> 6;
    const int r16 = lane & 15, kg = lane >> 4;

    const size_t base = (size_t)b * NSEQ * DIMC + (size_t)h * HD;

    const size_t qoff = base + (size_t)(n0 + w * 16 + r16) * DIMC + kg * 8;
    bf16x8 aq0 = *(const bf16x8*)&Q[qoff];
    bf16x8 aq1 = *(const bf16x8*)&Q[qoff + 32];

    const int krow = tid >> 1;
    const int kcol = (tid & 1) * 32;
    const unsigned short* Kg = K + base + (size_t)krow * DIMC + kcol;
    const int vkv = lane;
    const int vdc = w * 16;
    const unsigned short* Vg = V + base + (size_t)vkv * DIMC + vdc;

    f32x4 o[4] = {};
    float m_run = -1e30f, l_run = 0.f;

    ushort8 pk[4];
    ushort8 pv[2][2];

    auto pf_load = [&](size_t adv) {
        #pragma unroll
        for (int i = 0; i < 4; ++i) pk[i] = *(const ushort8*)(Kg + adv + 8 * i);
        #pragma unroll
        for (int rep = 0; rep < 2; ++rep)
            #pragma unroll
            for (int hh = 0; hh < 2; ++hh)
                pv[rep][hh] = *(const ushort8*)(Vg + adv + (size_t)rep * 64 * DIMC + hh * 8);
    };
    auto pf_write = [&]() {
        #pragma unroll
        for (int i = 0; i < 4; ++i) *(ushort8*)&Ks[krow][kcol + 8 * i] = pk[i];
        #pragma unroll
        for (int rep = 0; rep < 2; ++rep)
            #pragma unroll
            for (int hh = 0; hh < 2; ++hh)
                #pragma unroll
                for (int e = 0; e < 8; ++e)
                    Vt[vdc + hh * 8 + e][vkv + rep * 64] = pv[rep][hh][e];
    };

    pf_load(0);
    pf_write();
    __syncthreads();

    for (int m0 = 0; m0 < NSEQ; m0 += 128) {
        const bool more = (m0 + 128 < NSEQ);
        if (more) pf_load((size_t)(m0 + 128) * DIMC);
        __builtin_amdgcn_sched_barrier(0);

        f32x4 sv[8];
        #pragma unroll
        for (int f = 0; f < 8; ++f) sv[f] = (f32x4){0.f, 0.f, 0.f, 0.f};
        __builtin_amdgcn_s_setprio(1);
        #pragma unroll
        for (int f = 0; f < 8; ++f) {
            bf16x8 kb0 = *(const bf16x8*)&Ks[f * 16 + r16][kg * 8];
            bf16x8 kb1 = *(const bf16x8*)&Ks[f * 16 + r16][32 + kg * 8];
            sv[f] = MFMA16(kb0, aq0, sv[f]);
            sv[f] = MFMA16(kb1, aq1, sv[f]);
        }
        __builtin_amdgcn_s_setprio(0);

        float mf[8];
        #pragma unroll
        for (int f = 0; f < 8; ++f)
            mf[f] = fmaxf(fmaxf(sv[f][0], sv[f][1]), fmaxf(sv[f][2], sv[f][3]));
        float m01 = fmaxf(mf[0], mf[1]), m23 = fmaxf(mf[2], mf[3]);
        float m45 = fmaxf(mf[4], mf[5]), m67 = fmaxf(mf[6], mf[7]);
        float mt = fmaxf(fmaxf(m01, m23), fmaxf(m45, m67));
        mt = fmaxf(mt, __shfl_xor(mt, 16));
        mt = fmaxf(mt, __shfl_xor(mt, 32));

        const bool defer = __all(mt - m_run <= 8.0f);
        float corr = 1.f;
        if (!defer) {
            const float mn = fmaxf(m_run, mt);
            corr = exp2f(m_run - mn);
            m_run = mn;
        }

        float sf[8];
        #pragma unroll
        for (int f = 0; f < 8; ++f) {
            float p0 = exp2f(sv[f][0] - m_run);
            float p1 = exp2f(sv[f][1] - m_run);
            float p2 = exp2f(sv[f][2] - m_run);
            float p3 = exp2f(sv[f][3] - m_run);
            sf[f] = (p0 + p1) + (p2 + p3);
            u32 w0, w1;
            asm("v_cvt_pk_bf16_f32 %0, %1, %2" : "=v"(w0) : "v"(p0), "v"(p1));
            asm("v_cvt_pk_bf16_f32 %0, %1, %2" : "=v"(w1) : "v"(p2), "v"(p3));
            u32x2 pw; pw[0] = w0; pw[1] = w1;
            *(u32x2*)&Ps[w][r16][f * 16 + kg * 4] = pw;
        }
        float st = ((sf[0] + sf[1]) + (sf[2] + sf[3])) + ((sf[4] + sf[5]) + (sf[6] + sf[7]));
        st += __shfl_xor(st, 16);
        st += __shfl_xor(st, 32);
        l_run = l_run * corr + st;

        if (!defer) {
            #pragma unroll
            for (int jj = 0; jj < 4; ++jj) {
                const float cq = __shfl(corr, kg * 4 + jj);
                o[0][jj] *= cq; o[1][jj] *= cq; o[2][jj] *= cq; o[3][jj] *= cq;
            }
        }

        bf16x8 pa[4];
        #pragma unroll
        for (int s = 0; s < 4; ++s)
            pa[s] = *(const bf16x8*)&Ps[w][r16][s * 32 + kg * 8];
        __builtin_amdgcn_s_setprio(1);
        #pragma unroll
        for (int nj = 0; nj < 4; ++nj) {
            #pragma unroll
            for (int s = 0; s < 4; ++s) {
                bf16x8 vb = *(const bf16x8*)&Vt[nj * 16 + r16][s * 32 + kg * 8];
                o[nj] = MFMA16(pa[s], vb, o[nj]);
            }
        }
        __builtin_amdgcn_s_setprio(0);

        __builtin_amdgcn_s_barrier();
        __builtin_amdgcn_sched_barrier(0);
        if (more) pf_write();
        __syncthreads();
    }

    const float linv = 1.f / l_run;
    #pragma unroll
    for (int jj = 0; jj < 4; ++jj) {
        const float cq = __shfl(linv, kg * 4 + jj);
        #pragma unroll
        for (int nj = 0; nj < 4; ++nj) {
            const size_t go = base + (size_t)(n0 + w * 16 + kg * 4 + jj) * DIMC + nj * 16 + r16;
            O[go] = f2b(o[nj][jj] * cq);
        }
    }
}

// ---------------------------------------------------------------------------
// gate = sigmoid(G); fused = vis*g + Oc*(1-g); out = LN(fused).
// ---------------------------------------------------------------------------
__global__ __launch_bounds__(256)
void fuse_ln_kernel(const float* __restrict__ vis,
                    const float* __restrict__ Oc,
                    const float* __restrict__ G,
                    const float* __restrict__ w,
                    const float* __restrict__ b,
                    float* __restrict__ out)
{
    const int row = blockIdx.x;
    float f[3];
    float s = 0.f, q = 0.f;
    #pragma unroll
    for (int u = 0; u < 3; ++u) {
        const size_t idx = (size_t)row * DIMC + threadIdx.x + u * 256;
        const float vv = vis[idx];
        const float oo = Oc[idx];
        const float gg = 1.f / (1.f + __expf(-G[idx]));
        f[u] = vv * gg + oo * (1.f - gg);
        s += f[u];
        q += f[u] * f[u];
    }
    #pragma unroll
    for (int off = 32; off > 0; off >>= 1) {
        s += __shfl_down(s, off);
        q += __shfl_down(q, off);
    }
    __shared__ float ls[8];
    const int wv_ = threadIdx.x >> 6;
    if ((threadIdx.x & 63) == 0) { ls[wv_] = s; ls[4 + wv_] = q; }
    __syncthreads();
    if (threadIdx.x == 0) {
        ls[0] = ls[0] + ls[1] + ls[2] + ls[3];
        ls[4] = ls[4] + ls[5] + ls[6] + ls[7];
    }
    __syncthreads();
    const float mu  = ls[0] * (1.f / DIMC);
    const float var = ls[4] * (1.f / DIMC) - mu * mu;
    const float rs  = rsqrtf(var + EPSLN);
    #pragma unroll
    for (int u = 0; u < 3; ++u) {
        const int j = threadIdx.x + u * 256;
        out[(size_t)row * DIMC + j] = (f[u] - mu) * rs * w[j] + b[j];
    }
}

// ---------------------------------------------------------------------------
extern "C" void kernel_launch(void* const* d_in, const int* in_sizes, int n_in,
                              void* d_out, int out_size, void* d_ws, size_t ws_size,
                              hipStream_t stream)
{
    const float* vis  = (const float*)d_in[0];
    const float* inf_ = (const float*)d_in[1];
    const float* wq   = (const float*)d_in[2];
    const float* bq   = (const float*)d_in[3];
    const float* lnqw = (const float*)d_in[4];
    const float* lnqb = (const float*)d_in[5];
    const float* wk   = (const float*)d_in[6];
    const float* bk   = (const float*)d_in[7];
    const float* lnkw = (const float*)d_in[8];
    const float* lnkb = (const float*)d_in[9];
    const float* wv   = (const float*)d_in[10];
    const float* bv   = (const float*)d_in[11];
    const float* lnvw = (const float*)d_in[12];
    const float* lnvb = (const float*)d_in[13];
    const float* pos  = (const float*)d_in[14];
    const float* wo   = (const float*)d_in[15];
    const float* bo   = (const float*)d_in[16];
    const float* gw   = (const float*)d_in[17];
    const float* gb   = (const float*)d_in[18];
    const float* lnw  = (const float*)d_in[19];
    const float* lnb  = (const float*)d_in[20];

    const size_t WEL = 589824;                    // 768*768
    const size_t MWEL = 1769472;                  // 2304*768
    const size_t BUF = (size_t)NB * NSEQ * DIMC;  // 3145728

    // WS total = 43.9 MiB (safe < 51 proven; R6's 53.5 overflowed)
    unsigned short* p = (unsigned short*)d_ws;
    unsigned short* wq_b   = p;  p += WEL;
    unsigned short* mw_b   = p;  p += MWEL;   // [wk;wv;gw1]
    unsigned short* g2_b   = p;  p += WEL;    // gw2 bf16
    unsigned short* wo_b   = p;  p += WEL;    // wo bf16
    unsigned short* vis_b  = p;  p += BUF;
    unsigned short* inf_b  = p;  p += BUF;
    unsigned short* qpre_b = p;  p += BUF;    // pre-LN Q bf16; oc_b post-attn
    unsigned short* q_b    = p;  p += BUF;    // post-LN Q; attn O in place
    unsigned short* k_b    = p;  p += BUF;    // pre-LN K -> in-place LN'd K
    unsigned short* v_b    = p;  p += BUF;    // pre-LN V -> in-place LN'd V
    float* biasc = (float*)p;   p += 4608;    // [bk|bv|gb] f32 (2304)

    float* Gd = (float*)d_out;             // gate logits accumulator
    float* Oc = (float*)k_b;               // f32 O-proj (k_b+v_b, dead post-attn)
    unsigned short* oc_b = qpre_b;         // bf16 O-proj (qpre dead post-LN)

    dim3 blk(256);

    cast_all_kernel<<<dim3((G_ALL + 255) / 256), blk, 0, stream>>>(
        wq, wk, wv, gw, wo, bk, bv, gb, vis, inf_,
        wq_b, mw_b, g2_b, wo_b, vis_b, inf_b, biasc);

    // merged: Q-proj -> qpre_b | KVG -> k_b,v_b,Gd
    gemm_p1<<<dim3(1536), blk, 0, stream>>>(inf_b, vis_b, wq_b, mw_b,
                                            bq, biasc, qpre_b, k_b, v_b, Gd);

    // all three LayerNorms in one launch
    ln_all_kernel<<<dim3(12288), blk, 0, stream>>>(qpre_b, lnqw, lnqb, lnkw, lnkb,
                                                   lnvw, lnvb, pos, q_b, k_b, v_b);

    // attention (O overwrites q_b in place)
    attn_bf16_kernel<<<dim3(NB * NH, NSEQ / 64), blk, 0, stream>>>(q_b, k_b, v_b, q_b);

    // Oc = attnO@wo^T + bo (f32 + bf16)
    gemm_wo<<<dim3(384), blk, 0, stream>>>(q_b, wo_b, bo, Oc, oc_b);

    // Gd += Oc@gw2^T
    gemm_g2<<<dim3(384), blk, 0, stream>>>(oc_b, g2_b, Gd);

    // fuse + final LN -> d_out
    fuse_ln_kernel<<<dim3(4096), blk, 0, stream>>>(vis, Oc, Gd, lnw, lnb, (float*)d_out);
}